// Round 6
// baseline (2637.399 us; speedup 1.0000x reference)
//
#include <hip/hip_runtime.h>
#include <hip/hip_bf16.h>

#define NF 256
#define NH 128
#define NPART 8

typedef __attribute__((ext_vector_type(8))) short short8;
typedef __attribute__((ext_vector_type(4))) float float4v;

static __device__ __forceinline__ ushort f2bf(float f) {
  unsigned u = __float_as_uint(f);
  u = (u + 0x7fffu + ((u >> 16) & 1u)) >> 16;   // round-to-nearest-even
  return (ushort)u;
}
static __device__ __forceinline__ float bflo(unsigned u) { return __uint_as_float(u << 16); }
static __device__ __forceinline__ float bfhi(unsigned u) { return __uint_as_float(u & 0xffff0000u); }

static __device__ __forceinline__ short8 pack_bf8(float4 v0, float4 v1) {
  short8 r;
  r[0] = (short)f2bf(v0.x); r[1] = (short)f2bf(v0.y);
  r[2] = (short)f2bf(v0.z); r[3] = (short)f2bf(v0.w);
  r[4] = (short)f2bf(v1.x); r[5] = (short)f2bf(v1.y);
  r[6] = (short)f2bf(v1.z); r[7] = (short)f2bf(v1.w);
  return r;
}

// ---------------- init: per-part edge counts (blocks 0..63) + W1 B-fragments (64..191) + Wc (192) ----------------
__global__ __launch_bounds__(256) void k_init(
    const int* __restrict__ ei, int E, int psz, int* pcnt,
    const float* __restrict__ W1, ushort* __restrict__ Wfr,
    const float* __restrict__ W2, const float* __restrict__ Wfv,
    const float* __restrict__ b2, const float* __restrict__ bfv,
    float* __restrict__ Wc) {
  int b = blockIdx.x;
  if (b < 64) {
    __shared__ int hc[NPART];
    if (threadIdx.x < NPART) hc[threadIdx.x] = 0;
    __syncthreads();
    int lane = threadIdx.x & 63;
    int stride = 64 * 256;
    for (int e = b * 256 + threadIdx.x; e < E; e += stride) {
      int d = ei[E + e];
      int p = d / psz;
#pragma unroll
      for (int pp = 0; pp < NPART; ++pp) {
        unsigned long long m = __ballot(p == pp);
        if (p == pp && lane == __ffsll((unsigned long long)m) - 1)
          atomicAdd(&hc[pp], __popcll(m));
      }
    }
    __syncthreads();
    if (threadIdx.x < NPART && hc[threadIdx.x] > 0)
      atomicAdd(&pcnt[threadIdx.x], hc[threadIdx.x]);
  } else if (b < 64 + 128) {
    int g = (b - 64) * 256 + threadIdx.x;
    int ii   = g & 7;
    int lane = (g >> 3) & 63;
    int t    = (g >> 9) & 7;
    int ks   = g >> 12;
    int k = ks * 32 + ((lane >> 4) << 3) + ii;
    int c = t * 16 + (lane & 15);
    Wfr[g] = f2bf(W1[(size_t)k * NH + c]);
  } else {
    __shared__ float wl[NH];
    if (threadIdx.x < NH) wl[threadIdx.x] = Wfv[threadIdx.x];
    __syncthreads();
    if (threadIdx.x < NH) {
      int i = threadIdx.x;
      const float4* w4 = reinterpret_cast<const float4*>(&W2[(size_t)i * NH]);
      float s = 0.f;
#pragma unroll 8
      for (int k = 0; k < NH / 4; ++k) {
        float4 v = w4[k];
        s += v.x * wl[4 * k] + v.y * wl[4 * k + 1] + v.z * wl[4 * k + 2] + v.w * wl[4 * k + 3];
      }
      Wc[i] = s;
      if (i == 0) {
        float c = 0.f;
        for (int k = 0; k < NH; ++k) c += b2[k] * wl[k];
        Wc[NH] = c + bfv[0];
      }
    }
  }
}

// ---------------- split: edge list -> 8 per-part (s,d) sublists, ballot-aggregated append ----------------
__global__ __launch_bounds__(256) void k_split(
    const int* __restrict__ ei, const int* __restrict__ pcnt, int* tail,
    int2* __restrict__ sub, int E, int psz) {
  int pbase[NPART];
  {
    int run = 0;
#pragma unroll
    for (int p = 0; p < NPART; ++p) { pbase[p] = run; run += pcnt[p]; }
  }
  int lane = threadIdx.x & 63;
  int stride = gridDim.x * blockDim.x;
  for (int e = blockIdx.x * blockDim.x + threadIdx.x; e < E; e += stride) {
    int s = ei[e];
    int d = ei[E + e];
    int p = d / psz;
#pragma unroll
    for (int pp = 0; pp < NPART; ++pp) {
      unsigned long long m = __ballot(p == pp);
      if (p == pp) {
        int leader = __ffsll((unsigned long long)m) - 1;
        int base = 0;
        if (lane == leader) base = atomicAdd(&tail[pp], __popcll(m));
        base = __shfl(base, leader, 64);
        int rank = __popcll(m & ((1ull << lane) - 1ull));
        sub[pbase[pp] + base + rank] = make_int2(s, d);
      }
    }
  }
}

// ---------------- degree from own sublist (XCD-local atomics) ----------------
__global__ void k_deg_s(const int2* __restrict__ sub, const int* __restrict__ pcnt,
                        int* deg) {
  int part = blockIdx.x & (NPART - 1);
  int base = 0, cnt = 0;
#pragma unroll
  for (int p = 0; p < NPART; ++p) {
    int c = pcnt[p];
    if (p < part) base += c;
    if (p == part) cnt = c;
  }
  int stride = (gridDim.x >> 3) * blockDim.x;
  for (int e = (blockIdx.x >> 3) * blockDim.x + threadIdx.x; e < cnt; e += stride)
    atomicAdd(&deg[sub[base + e].y], 1);
}

// ---------------- scan pass 1: per-block sums of deg (1024/block) ----------------
__global__ __launch_bounds__(1024) void k_scan1(const int* __restrict__ deg, int* bsum, int N) {
  __shared__ int ws[16];
  int tid = threadIdx.x;
  int i = blockIdx.x * 1024 + tid;
  int d = (i < N) ? deg[i] : 0;
#pragma unroll
  for (int m = 1; m < 64; m <<= 1) d += __shfl_xor(d, m, 64);
  if ((tid & 63) == 0) ws[tid >> 6] = d;
  __syncthreads();
  if (tid < 64) {
    int v = (tid < 16) ? ws[tid] : 0;
#pragma unroll
    for (int m = 1; m < 16; m <<= 1) v += __shfl_xor(v, m, 64);
    if (tid == 0) bsum[blockIdx.x] = v;
  }
}

// ---------------- scan pass 2: rowptr/cursor; inline bsum prefix; dinv fused ----------------
__global__ __launch_bounds__(1024) void k_scan3(const int* __restrict__ deg,
                                                const int* __restrict__ bsum,
                                                int* rowptr, int* cursor,
                                                float* dinv, int N) {
  __shared__ int ws[17];
  int tid = threadIdx.x;
  int i = blockIdx.x * 1024 + tid;
  int lane = tid & 63, wid = tid >> 6;
  int d = (i < N) ? deg[i] : 0;
  int pre = d;
#pragma unroll
  for (int m = 1; m < 64; m <<= 1) {
    int t = __shfl_up(pre, m, 64);
    if (lane >= m) pre += t;
  }
  if (lane == 63) ws[wid] = pre;
  __syncthreads();
  if (wid == 0) {
    int v = (lane < 16) ? ws[lane] : 0;
#pragma unroll
    for (int m = 1; m < 16; m <<= 1) {
      int t = __shfl_up(v, m, 64);
      if (lane >= m) v += t;
    }
    if (lane < 16) ws[lane] = v;
  } else if (wid == 1) {
    int v = 0;
    for (int j = lane; j < blockIdx.x; j += 64) v += bsum[j];
#pragma unroll
    for (int m = 1; m < 64; m <<= 1) v += __shfl_xor(v, m, 64);
    if (lane == 0) ws[16] = v;
  }
  __syncthreads();
  int waveoff = (wid == 0) ? 0 : ws[wid - 1];
  if (i < N) {
    int excl = (pre - d) + waveoff + ws[16];
    rowptr[i] = excl;
    cursor[i] = excl;
    dinv[i] = rsqrtf((float)d + 1.0f);
  }
}

// ---------------- fill CSR from own sublist (XCD-local atomics + writes) ----------------
__global__ void k_fill_s(const int2* __restrict__ sub, const int* __restrict__ pcnt,
                         int* cursor, int* __restrict__ csr) {
  int part = blockIdx.x & (NPART - 1);
  int base = 0, cnt = 0;
#pragma unroll
  for (int p = 0; p < NPART; ++p) {
    int c = pcnt[p];
    if (p < part) base += c;
    if (p == part) cnt = c;
  }
  int stride = (gridDim.x >> 3) * blockDim.x;
  for (int e = (blockIdx.x >> 3) * blockDim.x + threadIdx.x; e < cnt; e += stride) {
    int2 sd = sub[base + e];
    csr[atomicAdd(&cursor[sd.y], 1)] = sd.x;
  }
}

// ---------------- GEMM1 (MFMA, no LDS staging): hs = dinv * (x @ W1), bf16 ----------------
__global__ __launch_bounds__(256) void k_gemm1(
    const float* __restrict__ x, const ushort* __restrict__ Wf,
    const float* __restrict__ dinv, ushort* __restrict__ hs, int N) {
  __shared__ ushort Ol[64][136];
  const int tid = threadIdx.x;
  const int w = tid >> 6, l = tid & 63;
  const int row0 = blockIdx.x * 64;
  const int arow = row0 + 16 * w + (l & 15);
  const int kg = l >> 4;
  const bool rv = arow < N;
  const float* xr = &x[(size_t)(rv ? arow : 0) * NF + kg * 8];

  short8 afr[8];
#pragma unroll
  for (int ks = 0; ks < 8; ++ks) {
    float4 v0 = make_float4(0.f, 0.f, 0.f, 0.f), v1 = v0;
    if (rv) {
      v0 = *reinterpret_cast<const float4*>(&xr[ks * 32]);
      v1 = *reinterpret_cast<const float4*>(&xr[ks * 32 + 4]);
    }
    afr[ks] = pack_bf8(v0, v1);
  }

  float4v acc[8];
#pragma unroll
  for (int t = 0; t < 8; ++t) acc[t] = (float4v){0.f, 0.f, 0.f, 0.f};
#pragma unroll
  for (int t = 0; t < 8; ++t) {
#pragma unroll
    for (int ks = 0; ks < 8; ++ks) {
      short8 b = *reinterpret_cast<const short8*>(&Wf[(size_t)(((ks * 8 + t) * 64 + l)) * 8]);
      acc[t] = __builtin_amdgcn_mfma_f32_16x16x32_bf16(afr[ks], b, acc[t], 0, 0, 0);
    }
  }

  float dj[4];
#pragma unroll
  for (int j = 0; j < 4; ++j) {
    int grow = row0 + 16 * w + (l >> 4) * 4 + j;
    dj[j] = (grow < N) ? dinv[grow] : 0.f;
  }
#pragma unroll
  for (int t = 0; t < 8; ++t)
#pragma unroll
    for (int j = 0; j < 4; ++j)
      Ol[16 * w + (l >> 4) * 4 + j][16 * t + (l & 15)] = f2bf(acc[t][j] * dj[j]);
  __syncthreads();
  {
    const int r = tid >> 2, grow = row0 + r;
    if (grow < N) {
      uint* dsts = (uint*)hs;
#pragma unroll
      for (int q = 0; q < 4; ++q) {
        uint4 v = *reinterpret_cast<const uint4*>(&Ol[r][(tid & 3) * 32 + q * 8]);
        *reinterpret_cast<uint4*>(&dsts[(size_t)grow * 64 + (tid & 3) * 16 + q * 4]) = v;
      }
    }
  }
}

// ---------------- fused layer1 gather + relu + dot(Wc): wave/node, quarter-wave edges ----------------
static __device__ __forceinline__ void acc8(float* a, uint4 u) {
  a[0] += bflo(u.x); a[1] += bfhi(u.x);
  a[2] += bflo(u.y); a[3] += bfhi(u.y);
  a[4] += bflo(u.z); a[5] += bfhi(u.z);
  a[6] += bflo(u.w); a[7] += bfhi(u.w);
}

__global__ __launch_bounds__(256) void k_agg1_z(
    const uint4* __restrict__ hs4, const int* __restrict__ rowptr,
    const int* __restrict__ deg, const int* __restrict__ csr,
    const float* __restrict__ dinv, const float* __restrict__ b1,
    const float* __restrict__ Wc, float* __restrict__ zs,
    float* __restrict__ out, int N) {
  int g = blockIdx.x * blockDim.x + threadIdx.x;
  int i = g >> 6;
  if (i >= N) return;
  int lane = threadIdx.x & 63;
  int q = lane >> 4;        // quarter 0..3 -> edge slot
  int sub = lane & 15;      // 16 lanes x uint4 = 128 features

  float a[8];
  {  // self-loop: quarter 0 only
    uint4 u = hs4[(size_t)i * 16 + sub];
    if (q) { u.x = 0u; u.y = 0u; u.z = 0u; u.w = 0u; }
    a[0] = bflo(u.x); a[1] = bfhi(u.x); a[2] = bflo(u.y); a[3] = bfhi(u.y);
    a[4] = bflo(u.z); a[5] = bfhi(u.z); a[6] = bflo(u.w); a[7] = bfhi(u.w);
  }

  int kk = rowptr[i];
  const int end = kk + deg[i];
  for (; kk + 7 < end; kk += 8) {     // 8 edges/iter, 2 per quarter
    int c0 = csr[kk + q];
    int c1 = csr[kk + 4 + q];
    uint4 u0 = hs4[(size_t)c0 * 16 + sub];
    uint4 u1 = hs4[(size_t)c1 * 16 + sub];
    acc8(a, u0);
    acc8(a, u1);
  }
  if (kk + 3 < end) {                 // 4 edges
    int c = csr[kk + q];
    uint4 u = hs4[(size_t)c * 16 + sub];
    acc8(a, u);
    kk += 4;
  }
  int r = end - kk;                   // 0..3 leftover
  if (r > 0) {
    int c = csr[kk + (q < r ? q : r - 1)];
    uint4 u = hs4[(size_t)c * 16 + sub];
    if (q >= r) { u.x = 0u; u.y = 0u; u.z = 0u; u.w = 0u; }
    acc8(a, u);
  }

#pragma unroll
  for (int j = 0; j < 8; ++j) {       // combine quarters
    a[j] += __shfl_xor(a[j], 16, 64);
    a[j] += __shfl_xor(a[j], 32, 64);
  }

  float d = dinv[i];
  float4 ba = reinterpret_cast<const float4*>(b1)[2 * sub];
  float4 bb = reinterpret_cast<const float4*>(b1)[2 * sub + 1];
  float4 wa = reinterpret_cast<const float4*>(Wc)[2 * sub];
  float4 wb = reinterpret_cast<const float4*>(Wc)[2 * sub + 1];
  float s = fmaxf(fmaf(d, a[0], ba.x), 0.f) * wa.x
          + fmaxf(fmaf(d, a[1], ba.y), 0.f) * wa.y
          + fmaxf(fmaf(d, a[2], ba.z), 0.f) * wa.z
          + fmaxf(fmaf(d, a[3], ba.w), 0.f) * wa.w
          + fmaxf(fmaf(d, a[4], bb.x), 0.f) * wb.x
          + fmaxf(fmaf(d, a[5], bb.y), 0.f) * wb.y
          + fmaxf(fmaf(d, a[6], bb.z), 0.f) * wb.z
          + fmaxf(fmaf(d, a[7], bb.w), 0.f) * wb.w;
#pragma unroll
  for (int m = 8; m >= 1; m >>= 1) s += __shfl_xor(s, m, 64);
  if (lane == 0) {
    float zsv = d * s;
    zs[i] = zsv;
    out[i] = d * zsv + Wc[NH];
  }
}

// ---------------- layer2 gather: out[i] += dinv[i] * sum zs[src] ----------------
__global__ void k_out2(const int* __restrict__ rowptr, const int* __restrict__ deg,
                       const int* __restrict__ csr, const float* __restrict__ zs,
                       const float* __restrict__ dinv, float* __restrict__ out, int N) {
  int i = blockIdx.x * blockDim.x + threadIdx.x;
  if (i >= N) return;
  int k = rowptr[i], end = k + deg[i];
  float s = 0.f;
  for (; k + 3 < end; k += 4) {
    float t0 = zs[csr[k]], t1 = zs[csr[k + 1]], t2 = zs[csr[k + 2]], t3 = zs[csr[k + 3]];
    s += (t0 + t1) + (t2 + t3);
  }
  for (; k < end; ++k) s += zs[csr[k]];
  out[i] += dinv[i] * s;
}

extern "C" void kernel_launch(void* const* d_in, const int* in_sizes, int n_in,
                              void* d_out, int out_size, void* d_ws, size_t ws_size,
                              hipStream_t stream) {
  const float* x  = (const float*)d_in[0];
  const int*   ei = (const int*)d_in[1];
  const float* W1 = (const float*)d_in[2];
  const float* b1 = (const float*)d_in[3];
  const float* W2 = (const float*)d_in[4];
  const float* b2 = (const float*)d_in[5];
  const float* Wf = (const float*)d_in[6];
  const float* bf = (const float*)d_in[7];
  const int N = in_sizes[0] / NF;
  const int E = in_sizes[1] / 2;
  const int psz = (N + NPART - 1) / NPART;
  const int nb = (N + 1023) / 1024;

  char* ws = (char*)d_ws;
  size_t off = 0;
  auto alloc = [&](size_t bytes) {
    void* p = ws + off;
    off = (off + bytes + 255) & ~(size_t)255;
    return p;
  };
  ushort* hs     = (ushort*)alloc((size_t)N * NH * 2);   // 25.6 MB
  ushort* Wfrag  = (ushort*)alloc((size_t)NF * NH * 2);  // 64 KB
  int*    csr    = (int*)alloc((size_t)E * 4);           // 6.4 MB
  int2*   sub    = (int2*)alloc((size_t)E * 8);          // 12.8 MB
  int*    deg    = (int*)alloc((size_t)N * 4 + 64);      // deg + pcnt(8) + tail(8)
  int*    pcnt   = deg + N;
  int*    tail   = deg + N + 8;
  int*    rowptr = (int*)alloc((size_t)N * 4);
  int*    cursor = (int*)alloc((size_t)N * 4);
  float*  dinv   = (float*)alloc((size_t)N * 4);
  float*  zs     = (float*)alloc((size_t)N * 4);
  float*  Wc     = (float*)alloc(132 * 4);
  int*    bsum   = (int*)alloc((size_t)nb * 4 + 64);
  float*  out    = (float*)d_out;

  const int b = 256;
  hipMemsetAsync(deg, 0, (size_t)N * 4 + 64, stream);
  k_init   <<<193, b, 0, stream>>>(ei, E, psz, pcnt, W1, Wfrag, W2, Wf, b2, bf, Wc);
  k_split  <<<1024, b, 0, stream>>>(ei, pcnt, tail, sub, E, psz);
  k_deg_s  <<<NPART * 64, b, 0, stream>>>(sub, pcnt, deg);
  k_scan1  <<<nb, 1024, 0, stream>>>(deg, bsum, N);
  k_scan3  <<<nb, 1024, 0, stream>>>(deg, bsum, rowptr, cursor, dinv, N);
  k_fill_s <<<NPART * 64, b, 0, stream>>>(sub, pcnt, cursor, csr);
  k_gemm1  <<<(N + 63) / 64, 256, 0, stream>>>(x, Wfrag, dinv, hs, N);
  k_agg1_z <<<(int)(((size_t)N * 64 + b - 1) / b), b, 0, stream>>>(
      (const uint4*)hs, rowptr, deg, csr, dinv, b1, Wc, zs, out, N);
  k_out2   <<<(N + b - 1) / b, b, 0, stream>>>(rowptr, deg, csr, zs, dinv, out, N);
}

// Round 7
// 292.283 us; speedup vs baseline: 9.0234x; 9.0234x over previous
//
#include <hip/hip_runtime.h>
#include <hip/hip_bf16.h>

#define NF 256
#define NH 128
#define NPART 8
#define NCB 1024

typedef __attribute__((ext_vector_type(8))) short short8;
typedef __attribute__((ext_vector_type(4))) float float4v;

static __device__ __forceinline__ ushort f2bf(float f) {
  unsigned u = __float_as_uint(f);
  u = (u + 0x7fffu + ((u >> 16) & 1u)) >> 16;   // round-to-nearest-even
  return (ushort)u;
}
static __device__ __forceinline__ float bflo(unsigned u) { return __uint_as_float(u << 16); }
static __device__ __forceinline__ float bfhi(unsigned u) { return __uint_as_float(u & 0xffff0000u); }

static __device__ __forceinline__ short8 pack_bf8(float4 v0, float4 v1) {
  short8 r;
  r[0] = (short)f2bf(v0.x); r[1] = (short)f2bf(v0.y);
  r[2] = (short)f2bf(v0.z); r[3] = (short)f2bf(v0.w);
  r[4] = (short)f2bf(v1.x); r[5] = (short)f2bf(v1.y);
  r[6] = (short)f2bf(v1.z); r[7] = (short)f2bf(v1.w);
  return r;
}

// ---------------- init: W1 B-fragments (blocks 0..127) + Wc (block 128) ----------------
__global__ __launch_bounds__(256) void k_init(
    const float* __restrict__ W1, ushort* __restrict__ Wfr,
    const float* __restrict__ W2, const float* __restrict__ Wfv,
    const float* __restrict__ b2, const float* __restrict__ bfv,
    float* __restrict__ Wc) {
  int b = blockIdx.x;
  if (b < 128) {
    int g = b * 256 + threadIdx.x;
    int ii   = g & 7;
    int lane = (g >> 3) & 63;
    int t    = (g >> 9) & 7;
    int ks   = g >> 12;
    int k = ks * 32 + ((lane >> 4) << 3) + ii;
    int c = t * 16 + (lane & 15);
    Wfr[g] = f2bf(W1[(size_t)k * NH + c]);
  } else {
    __shared__ float wl[NH];
    if (threadIdx.x < NH) wl[threadIdx.x] = Wfv[threadIdx.x];
    __syncthreads();
    if (threadIdx.x < NH) {
      int i = threadIdx.x;
      const float4* w4 = reinterpret_cast<const float4*>(&W2[(size_t)i * NH]);
      float s = 0.f;
#pragma unroll 8
      for (int k = 0; k < NH / 4; ++k) {
        float4 v = w4[k];
        s += v.x * wl[4 * k] + v.y * wl[4 * k + 1] + v.z * wl[4 * k + 2] + v.w * wl[4 * k + 3];
      }
      Wc[i] = s;
      if (i == 0) {
        float c = 0.f;
        for (int k = 0; k < NH; ++k) c += b2[k] * wl[k];
        Wc[NH] = c + bfv[0];
      }
    }
  }
}

// ---------------- count: per-block per-part histogram (LDS only) ----------------
__global__ __launch_bounds__(256) void k_count(const int* __restrict__ ei, int E, int psz,
                                               int* __restrict__ bcnt, int chunk) {
  __shared__ int hc[NPART];
  if (threadIdx.x < NPART) hc[threadIdx.x] = 0;
  __syncthreads();
  int start = blockIdx.x * chunk;
  int endE = min(start + chunk, E);
  for (int e = start + (int)threadIdx.x; e < endE; e += 256)
    atomicAdd(&hc[ei[E + e] / psz], 1);
  __syncthreads();
  if (threadIdx.x < NPART) bcnt[threadIdx.x * NCB + blockIdx.x] = hc[threadIdx.x];
}

// ---------------- scanp: bbase[p][b] = pbase[p] + prefix_b(bcnt[p][.]); pbase[9] ----------------
__global__ __launch_bounds__(1024) void k_scanp(const int* __restrict__ bcnt,
                                                int* __restrict__ bbase,
                                                int* __restrict__ pbase) {
  __shared__ int ws[16];
  int tid = threadIdx.x, lane = tid & 63, wid = tid >> 6;
  int run = 0;
  for (int p = 0; p < NPART; ++p) {
    int v = bcnt[p * NCB + tid];
    int pre = v;
#pragma unroll
    for (int m = 1; m < 64; m <<= 1) {
      int t = __shfl_up(pre, m, 64);
      if (lane >= m) pre += t;
    }
    if (lane == 63) ws[wid] = pre;
    __syncthreads();
    if (wid == 0) {
      int t0 = (lane < 16) ? ws[lane] : 0;
#pragma unroll
      for (int m = 1; m < 16; m <<= 1) {
        int t = __shfl_up(t0, m, 64);
        if (lane >= m) t0 += t;
      }
      if (lane < 16) ws[lane] = t0;    // inclusive wave sums
    }
    __syncthreads();
    int waveoff = (wid == 0) ? 0 : ws[wid - 1];
    bbase[p * NCB + tid] = run + (pre - v) + waveoff;
    if (tid == 0) pbase[p] = run;
    run += ws[15];
    __syncthreads();
  }
  if (tid == 0) pbase[NPART] = run;
}

// ---------------- scatter: edges -> part-bucketed sub, LDS cursors only ----------------
__global__ __launch_bounds__(256) void k_scatter(const int* __restrict__ ei, int E, int psz,
                                                 const int* __restrict__ bbase,
                                                 int2* __restrict__ sub, int chunk) {
  __shared__ int cur[NPART];
  if (threadIdx.x < NPART) cur[threadIdx.x] = bbase[threadIdx.x * NCB + blockIdx.x];
  __syncthreads();
  int start = blockIdx.x * chunk;
  int endE = min(start + chunk, E);
  for (int e = start + (int)threadIdx.x; e < endE; e += 256) {
    int s = ei[e];
    int d = ei[E + e];
    int pos = atomicAdd(&cur[d / psz], 1);
    sub[pos] = make_int2(s, d);
  }
}

// ---------------- degree from own sublist (XCD-local atomics) ----------------
__global__ void k_deg_s(const int2* __restrict__ sub, const int* __restrict__ pbase,
                        int* deg) {
  int part = blockIdx.x & (NPART - 1);
  int base = pbase[part];
  int cnt = pbase[part + 1] - base;
  int stride = (gridDim.x >> 3) * blockDim.x;
  for (int e = (blockIdx.x >> 3) * blockDim.x + threadIdx.x; e < cnt; e += stride)
    atomicAdd(&deg[sub[base + e].y], 1);
}

// ---------------- scan pass 1: per-block sums of deg (1024/block) ----------------
__global__ __launch_bounds__(1024) void k_scan1(const int* __restrict__ deg, int* bsum, int N) {
  __shared__ int ws[16];
  int tid = threadIdx.x;
  int i = blockIdx.x * 1024 + tid;
  int d = (i < N) ? deg[i] : 0;
#pragma unroll
  for (int m = 1; m < 64; m <<= 1) d += __shfl_xor(d, m, 64);
  if ((tid & 63) == 0) ws[tid >> 6] = d;
  __syncthreads();
  if (tid < 64) {
    int v = (tid < 16) ? ws[tid] : 0;
#pragma unroll
    for (int m = 1; m < 16; m <<= 1) v += __shfl_xor(v, m, 64);
    if (tid == 0) bsum[blockIdx.x] = v;
  }
}

// ---------------- scan pass 2: rowptr/cursor; inline bsum prefix; dinv fused ----------------
__global__ __launch_bounds__(1024) void k_scan3(const int* __restrict__ deg,
                                                const int* __restrict__ bsum,
                                                int* rowptr, int* cursor,
                                                float* dinv, int N) {
  __shared__ int ws[17];
  int tid = threadIdx.x;
  int i = blockIdx.x * 1024 + tid;
  int lane = tid & 63, wid = tid >> 6;
  int d = (i < N) ? deg[i] : 0;
  int pre = d;
#pragma unroll
  for (int m = 1; m < 64; m <<= 1) {
    int t = __shfl_up(pre, m, 64);
    if (lane >= m) pre += t;
  }
  if (lane == 63) ws[wid] = pre;
  __syncthreads();
  if (wid == 0) {
    int v = (lane < 16) ? ws[lane] : 0;
#pragma unroll
    for (int m = 1; m < 16; m <<= 1) {
      int t = __shfl_up(v, m, 64);
      if (lane >= m) v += t;
    }
    if (lane < 16) ws[lane] = v;
  } else if (wid == 1) {
    int v = 0;
    for (int j = lane; j < blockIdx.x; j += 64) v += bsum[j];
#pragma unroll
    for (int m = 1; m < 64; m <<= 1) v += __shfl_xor(v, m, 64);
    if (lane == 0) ws[16] = v;
  }
  __syncthreads();
  int waveoff = (wid == 0) ? 0 : ws[wid - 1];
  if (i < N) {
    int excl = (pre - d) + waveoff + ws[16];
    rowptr[i] = excl;
    cursor[i] = excl;
    dinv[i] = rsqrtf((float)d + 1.0f);
  }
}

// ---------------- fill CSR from own sublist (XCD-local atomics + writes) ----------------
__global__ void k_fill_s(const int2* __restrict__ sub, const int* __restrict__ pbase,
                         int* cursor, int* __restrict__ csr) {
  int part = blockIdx.x & (NPART - 1);
  int base = pbase[part];
  int cnt = pbase[part + 1] - base;
  int stride = (gridDim.x >> 3) * blockDim.x;
  for (int e = (blockIdx.x >> 3) * blockDim.x + threadIdx.x; e < cnt; e += stride) {
    int2 sd = sub[base + e];
    csr[atomicAdd(&cursor[sd.y], 1)] = sd.x;
  }
}

// ---------------- GEMM1 (MFMA, no LDS staging): hs = dinv * (x @ W1), bf16 ----------------
__global__ __launch_bounds__(256) void k_gemm1(
    const float* __restrict__ x, const ushort* __restrict__ Wf,
    const float* __restrict__ dinv, ushort* __restrict__ hs, int N) {
  __shared__ ushort Ol[64][136];
  const int tid = threadIdx.x;
  const int w = tid >> 6, l = tid & 63;
  const int row0 = blockIdx.x * 64;
  const int arow = row0 + 16 * w + (l & 15);
  const int kg = l >> 4;
  const bool rv = arow < N;
  const float* xr = &x[(size_t)(rv ? arow : 0) * NF + kg * 8];

  short8 afr[8];
#pragma unroll
  for (int ks = 0; ks < 8; ++ks) {
    float4 v0 = make_float4(0.f, 0.f, 0.f, 0.f), v1 = v0;
    if (rv) {
      v0 = *reinterpret_cast<const float4*>(&xr[ks * 32]);
      v1 = *reinterpret_cast<const float4*>(&xr[ks * 32 + 4]);
    }
    afr[ks] = pack_bf8(v0, v1);
  }

  float4v acc[8];
#pragma unroll
  for (int t = 0; t < 8; ++t) acc[t] = (float4v){0.f, 0.f, 0.f, 0.f};
#pragma unroll
  for (int t = 0; t < 8; ++t) {
#pragma unroll
    for (int ks = 0; ks < 8; ++ks) {
      short8 b = *reinterpret_cast<const short8*>(&Wf[(size_t)(((ks * 8 + t) * 64 + l)) * 8]);
      acc[t] = __builtin_amdgcn_mfma_f32_16x16x32_bf16(afr[ks], b, acc[t], 0, 0, 0);
    }
  }

  float dj[4];
#pragma unroll
  for (int j = 0; j < 4; ++j) {
    int grow = row0 + 16 * w + (l >> 4) * 4 + j;
    dj[j] = (grow < N) ? dinv[grow] : 0.f;
  }
#pragma unroll
  for (int t = 0; t < 8; ++t)
#pragma unroll
    for (int j = 0; j < 4; ++j)
      Ol[16 * w + (l >> 4) * 4 + j][16 * t + (l & 15)] = f2bf(acc[t][j] * dj[j]);
  __syncthreads();
  {
    const int r = tid >> 2, grow = row0 + r;
    if (grow < N) {
      uint* dsts = (uint*)hs;
#pragma unroll
      for (int q = 0; q < 4; ++q) {
        uint4 v = *reinterpret_cast<const uint4*>(&Ol[r][(tid & 3) * 32 + q * 8]);
        *reinterpret_cast<uint4*>(&dsts[(size_t)grow * 64 + (tid & 3) * 16 + q * 4]) = v;
      }
    }
  }
}

// ---------------- fused layer1 gather + relu + dot(Wc): wave/node, quarter-wave edges ----------------
static __device__ __forceinline__ void acc8(float* a, uint4 u) {
  a[0] += bflo(u.x); a[1] += bfhi(u.x);
  a[2] += bflo(u.y); a[3] += bfhi(u.y);
  a[4] += bflo(u.z); a[5] += bfhi(u.z);
  a[6] += bflo(u.w); a[7] += bfhi(u.w);
}

__global__ __launch_bounds__(256) void k_agg1_z(
    const uint4* __restrict__ hs4, const int* __restrict__ rowptr,
    const int* __restrict__ deg, const int* __restrict__ csr,
    const float* __restrict__ dinv, const float* __restrict__ b1,
    const float* __restrict__ Wc, float* __restrict__ zs,
    float* __restrict__ out, int N) {
  int g = blockIdx.x * blockDim.x + threadIdx.x;
  int i = g >> 6;
  if (i >= N) return;
  int lane = threadIdx.x & 63;
  int q = lane >> 4;        // quarter 0..3 -> edge slot
  int sub = lane & 15;      // 16 lanes x uint4 = 128 features

  float a[8];
  {  // self-loop: quarter 0 only
    uint4 u = hs4[(size_t)i * 16 + sub];
    if (q) { u.x = 0u; u.y = 0u; u.z = 0u; u.w = 0u; }
    a[0] = bflo(u.x); a[1] = bfhi(u.x); a[2] = bflo(u.y); a[3] = bfhi(u.y);
    a[4] = bflo(u.z); a[5] = bfhi(u.z); a[6] = bflo(u.w); a[7] = bfhi(u.w);
  }

  int kk = rowptr[i];
  const int end = kk + deg[i];
  for (; kk + 7 < end; kk += 8) {     // 8 edges/iter, 2 per quarter
    int c0 = csr[kk + q];
    int c1 = csr[kk + 4 + q];
    uint4 u0 = hs4[(size_t)c0 * 16 + sub];
    uint4 u1 = hs4[(size_t)c1 * 16 + sub];
    acc8(a, u0);
    acc8(a, u1);
  }
  if (kk + 3 < end) {                 // 4 edges
    int c = csr[kk + q];
    uint4 u = hs4[(size_t)c * 16 + sub];
    acc8(a, u);
    kk += 4;
  }
  int r = end - kk;                   // 0..3 leftover
  if (r > 0) {
    int c = csr[kk + (q < r ? q : r - 1)];
    uint4 u = hs4[(size_t)c * 16 + sub];
    if (q >= r) { u.x = 0u; u.y = 0u; u.z = 0u; u.w = 0u; }
    acc8(a, u);
  }

#pragma unroll
  for (int j = 0; j < 8; ++j) {       // combine quarters
    a[j] += __shfl_xor(a[j], 16, 64);
    a[j] += __shfl_xor(a[j], 32, 64);
  }

  float d = dinv[i];
  float4 ba = reinterpret_cast<const float4*>(b1)[2 * sub];
  float4 bb = reinterpret_cast<const float4*>(b1)[2 * sub + 1];
  float4 wa = reinterpret_cast<const float4*>(Wc)[2 * sub];
  float4 wb = reinterpret_cast<const float4*>(Wc)[2 * sub + 1];
  float s = fmaxf(fmaf(d, a[0], ba.x), 0.f) * wa.x
          + fmaxf(fmaf(d, a[1], ba.y), 0.f) * wa.y
          + fmaxf(fmaf(d, a[2], ba.z), 0.f) * wa.z
          + fmaxf(fmaf(d, a[3], ba.w), 0.f) * wa.w
          + fmaxf(fmaf(d, a[4], bb.x), 0.f) * wb.x
          + fmaxf(fmaf(d, a[5], bb.y), 0.f) * wb.y
          + fmaxf(fmaf(d, a[6], bb.z), 0.f) * wb.z
          + fmaxf(fmaf(d, a[7], bb.w), 0.f) * wb.w;
#pragma unroll
  for (int m = 8; m >= 1; m >>= 1) s += __shfl_xor(s, m, 64);
  if (lane == 0) {
    float zsv = d * s;
    zs[i] = zsv;
    out[i] = d * zsv + Wc[NH];
  }
}

// ---------------- layer2 gather: out[i] += dinv[i] * sum zs[src] ----------------
__global__ void k_out2(const int* __restrict__ rowptr, const int* __restrict__ deg,
                       const int* __restrict__ csr, const float* __restrict__ zs,
                       const float* __restrict__ dinv, float* __restrict__ out, int N) {
  int i = blockIdx.x * blockDim.x + threadIdx.x;
  if (i >= N) return;
  int k = rowptr[i], end = k + deg[i];
  float s = 0.f;
  for (; k + 3 < end; k += 4) {
    float t0 = zs[csr[k]], t1 = zs[csr[k + 1]], t2 = zs[csr[k + 2]], t3 = zs[csr[k + 3]];
    s += (t0 + t1) + (t2 + t3);
  }
  for (; k < end; ++k) s += zs[csr[k]];
  out[i] += dinv[i] * s;
}

extern "C" void kernel_launch(void* const* d_in, const int* in_sizes, int n_in,
                              void* d_out, int out_size, void* d_ws, size_t ws_size,
                              hipStream_t stream) {
  const float* x  = (const float*)d_in[0];
  const int*   ei = (const int*)d_in[1];
  const float* W1 = (const float*)d_in[2];
  const float* b1 = (const float*)d_in[3];
  const float* W2 = (const float*)d_in[4];
  const float* b2 = (const float*)d_in[5];
  const float* Wf = (const float*)d_in[6];
  const float* bf = (const float*)d_in[7];
  const int N = in_sizes[0] / NF;
  const int E = in_sizes[1] / 2;
  const int psz = (N + NPART - 1) / NPART;
  const int nb = (N + 1023) / 1024;
  const int chunk = (E + NCB - 1) / NCB;

  char* ws = (char*)d_ws;
  size_t off = 0;
  auto alloc = [&](size_t bytes) {
    void* p = ws + off;
    off = (off + bytes + 255) & ~(size_t)255;
    return p;
  };
  ushort* hs     = (ushort*)alloc((size_t)N * NH * 2);    // 25.6 MB
  ushort* Wfrag  = (ushort*)alloc((size_t)NF * NH * 2);   // 64 KB
  int*    csr    = (int*)alloc((size_t)E * 4);            // 6.4 MB
  int2*   sub    = (int2*)alloc((size_t)E * 8);           // 12.8 MB
  int*    deg    = (int*)alloc((size_t)N * 4);
  int*    rowptr = (int*)alloc((size_t)N * 4);
  int*    cursor = (int*)alloc((size_t)N * 4);
  float*  dinv   = (float*)alloc((size_t)N * 4);
  float*  zs     = (float*)alloc((size_t)N * 4);
  float*  Wc     = (float*)alloc(132 * 4);
  int*    bcnt   = (int*)alloc((size_t)NPART * NCB * 4);  // 32 KB
  int*    bbase  = (int*)alloc((size_t)NPART * NCB * 4);  // 32 KB
  int*    pbase  = (int*)alloc((NPART + 1) * 4);
  int*    bsum   = (int*)alloc((size_t)nb * 4 + 64);
  float*  out    = (float*)d_out;

  const int b = 256;
  hipMemsetAsync(deg, 0, (size_t)N * 4, stream);
  k_init   <<<129, b, 0, stream>>>(W1, Wfrag, W2, Wf, b2, bf, Wc);
  k_count  <<<NCB, b, 0, stream>>>(ei, E, psz, bcnt, chunk);
  k_scanp  <<<1, 1024, 0, stream>>>(bcnt, bbase, pbase);
  k_scatter<<<NCB, b, 0, stream>>>(ei, E, psz, bbase, sub, chunk);
  k_deg_s  <<<NPART * 64, b, 0, stream>>>(sub, pbase, deg);
  k_scan1  <<<nb, 1024, 0, stream>>>(deg, bsum, N);
  k_scan3  <<<nb, 1024, 0, stream>>>(deg, bsum, rowptr, cursor, dinv, N);
  k_fill_s <<<NPART * 64, b, 0, stream>>>(sub, pbase, cursor, csr);
  k_gemm1  <<<(N + 63) / 64, 256, 0, stream>>>(x, Wfrag, dinv, hs, N);
  k_agg1_z <<<(int)(((size_t)N * 64 + b - 1) / b), b, 0, stream>>>(
      (const uint4*)hs, rowptr, deg, csr, dinv, b1, Wc, zs, out, N);
  k_out2   <<<(N + b - 1) / b, b, 0, stream>>>(rowptr, deg, csr, zs, dinv, out, N);
}

// Round 8
// 269.276 us; speedup vs baseline: 9.7944x; 1.0854x over previous
//
#include <hip/hip_runtime.h>
#include <hip/hip_bf16.h>

#define NF 256
#define NH 128
#define NPART 8
#define NCB 1024

typedef __attribute__((ext_vector_type(8))) short short8;
typedef __attribute__((ext_vector_type(4))) float float4v;

static __device__ __forceinline__ ushort f2bf(float f) {
  unsigned u = __float_as_uint(f);
  u = (u + 0x7fffu + ((u >> 16) & 1u)) >> 16;   // round-to-nearest-even
  return (ushort)u;
}
static __device__ __forceinline__ float bflo(unsigned u) { return __uint_as_float(u << 16); }
static __device__ __forceinline__ float bfhi(unsigned u) { return __uint_as_float(u & 0xffff0000u); }

static __device__ __forceinline__ short8 pack_bf8(float4 v0, float4 v1) {
  short8 r;
  r[0] = (short)f2bf(v0.x); r[1] = (short)f2bf(v0.y);
  r[2] = (short)f2bf(v0.z); r[3] = (short)f2bf(v0.w);
  r[4] = (short)f2bf(v1.x); r[5] = (short)f2bf(v1.y);
  r[6] = (short)f2bf(v1.z); r[7] = (short)f2bf(v1.w);
  return r;
}

// ------- initall: deg zero [0,nzb) | W1 frags [nzb,nzb+128) | Wc [nzb+128] | count [nzb+129, +NCB) -------
__global__ __launch_bounds__(256) void k_initall(
    int* deg, int N, int nzb,
    const int* __restrict__ ei, int E, int psz, int* __restrict__ bcnt, int chunk,
    const float* __restrict__ W1, ushort* __restrict__ Wfr,
    const float* __restrict__ W2, const float* __restrict__ Wfv,
    const float* __restrict__ b2, const float* __restrict__ bfv,
    float* __restrict__ Wc) {
  int b = blockIdx.x;
  if (b < nzb) {
    int i = b * 256 + threadIdx.x;
    if (i < N) deg[i] = 0;
  } else if (b < nzb + 128) {
    int g = (b - nzb) * 256 + threadIdx.x;
    int ii   = g & 7;
    int lane = (g >> 3) & 63;
    int t    = (g >> 9) & 7;
    int ks   = g >> 12;
    int k = ks * 32 + ((lane >> 4) << 3) + ii;
    int c = t * 16 + (lane & 15);
    Wfr[g] = f2bf(W1[(size_t)k * NH + c]);
  } else if (b == nzb + 128) {
    __shared__ float wl[NH];
    if (threadIdx.x < NH) wl[threadIdx.x] = Wfv[threadIdx.x];
    __syncthreads();
    if (threadIdx.x < NH) {
      int i = threadIdx.x;
      const float4* w4 = reinterpret_cast<const float4*>(&W2[(size_t)i * NH]);
      float s = 0.f;
#pragma unroll 8
      for (int k = 0; k < NH / 4; ++k) {
        float4 v = w4[k];
        s += v.x * wl[4 * k] + v.y * wl[4 * k + 1] + v.z * wl[4 * k + 2] + v.w * wl[4 * k + 3];
      }
      Wc[i] = s;
      if (i == 0) {
        float c = 0.f;
        for (int k = 0; k < NH; ++k) c += b2[k] * wl[k];
        Wc[NH] = c + bfv[0];
      }
    }
  } else {
    int cb = b - (nzb + 129);
    __shared__ int hc[NPART];
    if (threadIdx.x < NPART) hc[threadIdx.x] = 0;
    __syncthreads();
    int start = cb * chunk;
    int endE = min(start + chunk, E);
    for (int e = start + (int)threadIdx.x; e < endE; e += 256)
      atomicAdd(&hc[ei[E + e] / psz], 1);
    __syncthreads();
    if (threadIdx.x < NPART) bcnt[threadIdx.x * NCB + cb] = hc[threadIdx.x];
  }
}

// ---------------- scanp: bbase[p][b] = pbase[p] + prefix_b(bcnt[p][.]); pbase[9] ----------------
__global__ __launch_bounds__(1024) void k_scanp(const int* __restrict__ bcnt,
                                                int* __restrict__ bbase,
                                                int* __restrict__ pbase) {
  __shared__ int ws[16];
  int tid = threadIdx.x, lane = tid & 63, wid = tid >> 6;
  int run = 0;
  for (int p = 0; p < NPART; ++p) {
    int v = bcnt[p * NCB + tid];
    int pre = v;
#pragma unroll
    for (int m = 1; m < 64; m <<= 1) {
      int t = __shfl_up(pre, m, 64);
      if (lane >= m) pre += t;
    }
    if (lane == 63) ws[wid] = pre;
    __syncthreads();
    if (wid == 0) {
      int t0 = (lane < 16) ? ws[lane] : 0;
#pragma unroll
      for (int m = 1; m < 16; m <<= 1) {
        int t = __shfl_up(t0, m, 64);
        if (lane >= m) t0 += t;
      }
      if (lane < 16) ws[lane] = t0;    // inclusive wave sums
    }
    __syncthreads();
    int waveoff = (wid == 0) ? 0 : ws[wid - 1];
    bbase[p * NCB + tid] = run + (pre - v) + waveoff;
    if (tid == 0) pbase[p] = run;
    run += ws[15];
    __syncthreads();
  }
  if (tid == 0) pbase[NPART] = run;
}

// ---------------- scatter: edges -> part-bucketed sub, LDS cursors only ----------------
__global__ __launch_bounds__(256) void k_scatter(const int* __restrict__ ei, int E, int psz,
                                                 const int* __restrict__ bbase,
                                                 int2* __restrict__ sub, int chunk) {
  __shared__ int cur[NPART];
  if (threadIdx.x < NPART) cur[threadIdx.x] = bbase[threadIdx.x * NCB + blockIdx.x];
  __syncthreads();
  int start = blockIdx.x * chunk;
  int endE = min(start + chunk, E);
  for (int e = start + (int)threadIdx.x; e < endE; e += 256) {
    int s = ei[e];
    int d = ei[E + e];
    int pos = atomicAdd(&cur[d / psz], 1);
    sub[pos] = make_int2(s, d);
  }
}

// ---------------- degree from own sublist (XCD-local atomics) ----------------
__global__ void k_deg_s(const int2* __restrict__ sub, const int* __restrict__ pbase,
                        int* deg) {
  int part = blockIdx.x & (NPART - 1);
  int base = pbase[part];
  int cnt = pbase[part + 1] - base;
  int stride = (gridDim.x >> 3) * blockDim.x;
  for (int e = (blockIdx.x >> 3) * blockDim.x + threadIdx.x; e < cnt; e += stride)
    atomicAdd(&deg[sub[base + e].y], 1);
}

// ---------------- scan pass 1: per-block sums of deg (1024/block) ----------------
__global__ __launch_bounds__(1024) void k_scan1(const int* __restrict__ deg, int* bsum, int N) {
  __shared__ int ws[16];
  int tid = threadIdx.x;
  int i = blockIdx.x * 1024 + tid;
  int d = (i < N) ? deg[i] : 0;
#pragma unroll
  for (int m = 1; m < 64; m <<= 1) d += __shfl_xor(d, m, 64);
  if ((tid & 63) == 0) ws[tid >> 6] = d;
  __syncthreads();
  if (tid < 64) {
    int v = (tid < 16) ? ws[tid] : 0;
#pragma unroll
    for (int m = 1; m < 16; m <<= 1) v += __shfl_xor(v, m, 64);
    if (tid == 0) bsum[blockIdx.x] = v;
  }
}

// ---------------- scan pass 2: rowptr/cursor; inline bsum prefix; dinv fused ----------------
__global__ __launch_bounds__(1024) void k_scan3(const int* __restrict__ deg,
                                                const int* __restrict__ bsum,
                                                int* rowptr, int* cursor,
                                                float* dinv, int N) {
  __shared__ int ws[17];
  int tid = threadIdx.x;
  int i = blockIdx.x * 1024 + tid;
  int lane = tid & 63, wid = tid >> 6;
  int d = (i < N) ? deg[i] : 0;
  int pre = d;
#pragma unroll
  for (int m = 1; m < 64; m <<= 1) {
    int t = __shfl_up(pre, m, 64);
    if (lane >= m) pre += t;
  }
  if (lane == 63) ws[wid] = pre;
  __syncthreads();
  if (wid == 0) {
    int v = (lane < 16) ? ws[lane] : 0;
#pragma unroll
    for (int m = 1; m < 16; m <<= 1) {
      int t = __shfl_up(v, m, 64);
      if (lane >= m) v += t;
    }
    if (lane < 16) ws[lane] = v;
  } else if (wid == 1) {
    int v = 0;
    for (int j = lane; j < blockIdx.x; j += 64) v += bsum[j];
#pragma unroll
    for (int m = 1; m < 64; m <<= 1) v += __shfl_xor(v, m, 64);
    if (lane == 0) ws[16] = v;
  }
  __syncthreads();
  int waveoff = (wid == 0) ? 0 : ws[wid - 1];
  if (i < N) {
    int excl = (pre - d) + waveoff + ws[16];
    rowptr[i] = excl;
    cursor[i] = excl;
    dinv[i] = rsqrtf((float)d + 1.0f);
  }
}

// ---------------- fill CSR from own sublist (XCD-local atomics + writes) ----------------
__global__ void k_fill_s(const int2* __restrict__ sub, const int* __restrict__ pbase,
                         int* cursor, int* __restrict__ csr) {
  int part = blockIdx.x & (NPART - 1);
  int base = pbase[part];
  int cnt = pbase[part + 1] - base;
  int stride = (gridDim.x >> 3) * blockDim.x;
  for (int e = (blockIdx.x >> 3) * blockDim.x + threadIdx.x; e < cnt; e += stride) {
    int2 sd = sub[base + e];
    csr[atomicAdd(&cursor[sd.y], 1)] = sd.x;
  }
}

// ---------------- GEMM1 v3 (MFMA, phase-split MLP): hs = dinv * (x @ W1), bf16 ----------------
__global__ __launch_bounds__(256, 2) void k_gemm1(
    const float* __restrict__ x, const ushort* __restrict__ Wf,
    const float* __restrict__ dinv, ushort* __restrict__ hs, int N) {
  __shared__ ushort Ol[64][136];
  const int tid = threadIdx.x;
  const int w = tid >> 6, l = tid & 63;
  const int row0 = blockIdx.x * 64;
  const int arow = row0 + 16 * w + (l & 15);
  const int kg = l >> 4;
  const bool rv = arow < N;
  const float* xr = &x[(size_t)(rv ? arow : 0) * NF + kg * 8];

  // phase 1: issue ALL 16 x-loads (kept in flight; sched_barrier pins them before any use)
  float4 xf0[8], xf1[8];
#pragma unroll
  for (int ks = 0; ks < 8; ++ks) {
    xf0[ks] = *reinterpret_cast<const float4*>(&xr[ks * 32]);
    xf1[ks] = *reinterpret_cast<const float4*>(&xr[ks * 32 + 4]);
  }
  __builtin_amdgcn_sched_barrier(0);

  // phase 2: pack to bf16 A-fragments (zero invalid rows)
  short8 afr[8];
#pragma unroll
  for (int ks = 0; ks < 8; ++ks) {
    float4 v0 = xf0[ks], v1 = xf1[ks];
    if (!rv) { v0 = make_float4(0.f, 0.f, 0.f, 0.f); v1 = v0; }
    afr[ks] = pack_bf8(v0, v1);
  }

  // phase 3: MFMA with double-buffered B fragments (8 L2 loads in flight behind 8 MFMAs)
  const short8* Wb = reinterpret_cast<const short8*>(Wf);   // index: (ks*8 + t)*64 + l
  float4v acc[8];
#pragma unroll
  for (int t = 0; t < 8; ++t) acc[t] = (float4v){0.f, 0.f, 0.f, 0.f};
  short8 bc[8], bn[8];
#pragma unroll
  for (int ks = 0; ks < 8; ++ks) bc[ks] = Wb[(ks * 8 + 0) * 64 + l];
#pragma unroll
  for (int tp = 0; tp < 4; ++tp) {
    const int t0 = 2 * tp, t1 = 2 * tp + 1;
#pragma unroll
    for (int ks = 0; ks < 8; ++ks) bn[ks] = Wb[(ks * 8 + t1) * 64 + l];
    __builtin_amdgcn_sched_barrier(0);
#pragma unroll
    for (int ks = 0; ks < 8; ++ks)
      acc[t0] = __builtin_amdgcn_mfma_f32_16x16x32_bf16(afr[ks], bc[ks], acc[t0], 0, 0, 0);
    if (tp < 3) {
#pragma unroll
      for (int ks = 0; ks < 8; ++ks) bc[ks] = Wb[(ks * 8 + t1 + 1) * 64 + l];
      __builtin_amdgcn_sched_barrier(0);
    }
#pragma unroll
    for (int ks = 0; ks < 8; ++ks)
      acc[t1] = __builtin_amdgcn_mfma_f32_16x16x32_bf16(afr[ks], bn[ks], acc[t1], 0, 0, 0);
  }

  // epilogue: scale by dinv, bf16, transpose via LDS, coalesced store
  float dj[4];
#pragma unroll
  for (int j = 0; j < 4; ++j) {
    int grow = row0 + 16 * w + (l >> 4) * 4 + j;
    dj[j] = (grow < N) ? dinv[grow] : 0.f;
  }
#pragma unroll
  for (int t = 0; t < 8; ++t)
#pragma unroll
    for (int j = 0; j < 4; ++j)
      Ol[16 * w + (l >> 4) * 4 + j][16 * t + (l & 15)] = f2bf(acc[t][j] * dj[j]);
  __syncthreads();
  {
    const int r = tid >> 2, grow = row0 + r;
    if (grow < N) {
      uint* dsts = (uint*)hs;
#pragma unroll
      for (int q = 0; q < 4; ++q) {
        uint4 v = *reinterpret_cast<const uint4*>(&Ol[r][(tid & 3) * 32 + q * 8]);
        *reinterpret_cast<uint4*>(&dsts[(size_t)grow * 64 + (tid & 3) * 16 + q * 4]) = v;
      }
    }
  }
}

// ---------------- fused layer1 gather + relu + dot(Wc): wave/node, quarter-wave edges ----------------
static __device__ __forceinline__ void acc8(float* a, uint4 u) {
  a[0] += bflo(u.x); a[1] += bfhi(u.x);
  a[2] += bflo(u.y); a[3] += bfhi(u.y);
  a[4] += bflo(u.z); a[5] += bfhi(u.z);
  a[6] += bflo(u.w); a[7] += bfhi(u.w);
}

__global__ __launch_bounds__(256) void k_agg1_z(
    const uint4* __restrict__ hs4, const int* __restrict__ rowptr,
    const int* __restrict__ deg, const int* __restrict__ csr,
    const float* __restrict__ dinv, const float* __restrict__ b1,
    const float* __restrict__ Wc, float* __restrict__ zs,
    float* __restrict__ out, int N) {
  int g = blockIdx.x * blockDim.x + threadIdx.x;
  int i = g >> 6;
  if (i >= N) return;
  int lane = threadIdx.x & 63;
  int q = lane >> 4;        // quarter 0..3 -> edge slot
  int sub = lane & 15;      // 16 lanes x uint4 = 128 features

  float a[8];
  {  // self-loop: quarter 0 only
    uint4 u = hs4[(size_t)i * 16 + sub];
    if (q) { u.x = 0u; u.y = 0u; u.z = 0u; u.w = 0u; }
    a[0] = bflo(u.x); a[1] = bfhi(u.x); a[2] = bflo(u.y); a[3] = bfhi(u.y);
    a[4] = bflo(u.z); a[5] = bfhi(u.z); a[6] = bflo(u.w); a[7] = bfhi(u.w);
  }

  int kk = rowptr[i];
  const int end = kk + deg[i];
  for (; kk + 7 < end; kk += 8) {     // 8 edges/iter, 2 per quarter
    int c0 = csr[kk + q];
    int c1 = csr[kk + 4 + q];
    uint4 u0 = hs4[(size_t)c0 * 16 + sub];
    uint4 u1 = hs4[(size_t)c1 * 16 + sub];
    acc8(a, u0);
    acc8(a, u1);
  }
  if (kk + 3 < end) {                 // 4 edges
    int c = csr[kk + q];
    uint4 u = hs4[(size_t)c * 16 + sub];
    acc8(a, u);
    kk += 4;
  }
  int r = end - kk;                   // 0..3 leftover
  if (r > 0) {
    int c = csr[kk + (q < r ? q : r - 1)];
    uint4 u = hs4[(size_t)c * 16 + sub];
    if (q >= r) { u.x = 0u; u.y = 0u; u.z = 0u; u.w = 0u; }
    acc8(a, u);
  }

#pragma unroll
  for (int j = 0; j < 8; ++j) {       // combine quarters
    a[j] += __shfl_xor(a[j], 16, 64);
    a[j] += __shfl_xor(a[j], 32, 64);
  }

  float d = dinv[i];
  float4 ba = reinterpret_cast<const float4*>(b1)[2 * sub];
  float4 bb = reinterpret_cast<const float4*>(b1)[2 * sub + 1];
  float4 wa = reinterpret_cast<const float4*>(Wc)[2 * sub];
  float4 wb = reinterpret_cast<const float4*>(Wc)[2 * sub + 1];
  float s = fmaxf(fmaf(d, a[0], ba.x), 0.f) * wa.x
          + fmaxf(fmaf(d, a[1], ba.y), 0.f) * wa.y
          + fmaxf(fmaf(d, a[2], ba.z), 0.f) * wa.z
          + fmaxf(fmaf(d, a[3], ba.w), 0.f) * wa.w
          + fmaxf(fmaf(d, a[4], bb.x), 0.f) * wb.x
          + fmaxf(fmaf(d, a[5], bb.y), 0.f) * wb.y
          + fmaxf(fmaf(d, a[6], bb.z), 0.f) * wb.z
          + fmaxf(fmaf(d, a[7], bb.w), 0.f) * wb.w;
#pragma unroll
  for (int m = 8; m >= 1; m >>= 1) s += __shfl_xor(s, m, 64);
  if (lane == 0) {
    float zsv = d * s;
    zs[i] = zsv;
    out[i] = d * zsv + Wc[NH];
  }
}

// ---------------- layer2 gather: out[i] += dinv[i] * sum zs[src] ----------------
__global__ void k_out2(const int* __restrict__ rowptr, const int* __restrict__ deg,
                       const int* __restrict__ csr, const float* __restrict__ zs,
                       const float* __restrict__ dinv, float* __restrict__ out, int N) {
  int i = blockIdx.x * blockDim.x + threadIdx.x;
  if (i >= N) return;
  int k = rowptr[i], end = k + deg[i];
  float s = 0.f;
  for (; k + 3 < end; k += 4) {
    float t0 = zs[csr[k]], t1 = zs[csr[k + 1]], t2 = zs[csr[k + 2]], t3 = zs[csr[k + 3]];
    s += (t0 + t1) + (t2 + t3);
  }
  for (; k < end; ++k) s += zs[csr[k]];
  out[i] += dinv[i] * s;
}

extern "C" void kernel_launch(void* const* d_in, const int* in_sizes, int n_in,
                              void* d_out, int out_size, void* d_ws, size_t ws_size,
                              hipStream_t stream) {
  const float* x  = (const float*)d_in[0];
  const int*   ei = (const int*)d_in[1];
  const float* W1 = (const float*)d_in[2];
  const float* b1 = (const float*)d_in[3];
  const float* W2 = (const float*)d_in[4];
  const float* b2 = (const float*)d_in[5];
  const float* Wf = (const float*)d_in[6];
  const float* bf = (const float*)d_in[7];
  const int N = in_sizes[0] / NF;
  const int E = in_sizes[1] / 2;
  const int psz = (N + NPART - 1) / NPART;
  const int nb = (N + 1023) / 1024;
  const int nzb = (N + 255) / 256;
  const int chunk = (E + NCB - 1) / NCB;

  char* ws = (char*)d_ws;
  size_t off = 0;
  auto alloc = [&](size_t bytes) {
    void* p = ws + off;
    off = (off + bytes + 255) & ~(size_t)255;
    return p;
  };
  ushort* hs     = (ushort*)alloc((size_t)N * NH * 2);    // 25.6 MB
  ushort* Wfrag  = (ushort*)alloc((size_t)NF * NH * 2);   // 64 KB
  int*    csr    = (int*)alloc((size_t)E * 4);            // 6.4 MB
  int2*   sub    = (int2*)alloc((size_t)E * 8);           // 12.8 MB
  int*    deg    = (int*)alloc((size_t)N * 4);
  int*    rowptr = (int*)alloc((size_t)N * 4);
  int*    cursor = (int*)alloc((size_t)N * 4);
  float*  dinv   = (float*)alloc((size_t)N * 4);
  float*  zs     = (float*)alloc((size_t)N * 4);
  float*  Wc     = (float*)alloc(132 * 4);
  int*    bcnt   = (int*)alloc((size_t)NPART * NCB * 4);  // 32 KB
  int*    bbase  = (int*)alloc((size_t)NPART * NCB * 4);  // 32 KB
  int*    pbase  = (int*)alloc((NPART + 1) * 4);
  int*    bsum   = (int*)alloc((size_t)nb * 4 + 64);
  float*  out    = (float*)d_out;

  const int b = 256;
  k_initall<<<nzb + 129 + NCB, b, 0, stream>>>(deg, N, nzb, ei, E, psz, bcnt, chunk,
                                               W1, Wfrag, W2, Wf, b2, bf, Wc);
  k_scanp  <<<1, 1024, 0, stream>>>(bcnt, bbase, pbase);
  k_scatter<<<NCB, b, 0, stream>>>(ei, E, psz, bbase, sub, chunk);
  k_deg_s  <<<NPART * 64, b, 0, stream>>>(sub, pbase, deg);
  k_scan1  <<<nb, 1024, 0, stream>>>(deg, bsum, N);
  k_scan3  <<<nb, 1024, 0, stream>>>(deg, bsum, rowptr, cursor, dinv, N);
  k_fill_s <<<NPART * 64, b, 0, stream>>>(sub, pbase, cursor, csr);
  k_gemm1  <<<(N + 63) / 64, 256, 0, stream>>>(x, Wfrag, dinv, hs, N);
  k_agg1_z <<<(int)(((size_t)N * 64 + b - 1) / b), b, 0, stream>>>(
      (const uint4*)hs, rowptr, deg, csr, dinv, b1, Wc, zs, out, N);
  k_out2   <<<(N + b - 1) / b, b, 0, stream>>>(rowptr, deg, csr, zs, dinv, out, N);
}

// Round 9
// 159.088 us; speedup vs baseline: 16.5782x; 1.6926x over previous
//
#include <hip/hip_runtime.h>
#include <hip/hip_bf16.h>

#define NF 256
#define NH 128
#define PSZ_SH 7            // 128 nodes per bucket
#define MAXP 1024           // max buckets (N <= 131072)
#define NCB 512             // chunk blocks for count/scatter

typedef __attribute__((ext_vector_type(8))) short short8;
typedef __attribute__((ext_vector_type(4))) float float4v;

static __device__ __forceinline__ ushort f2bf(float f) {
  unsigned u = __float_as_uint(f);
  u = (u + 0x7fffu + ((u >> 16) & 1u)) >> 16;   // round-to-nearest-even
  return (ushort)u;
}
static __device__ __forceinline__ float bflo(unsigned u) { return __uint_as_float(u << 16); }
static __device__ __forceinline__ float bfhi(unsigned u) { return __uint_as_float(u & 0xffff0000u); }

static __device__ __forceinline__ short8 pack_bf8(float4 v0, float4 v1) {
  short8 r;
  r[0] = (short)f2bf(v0.x); r[1] = (short)f2bf(v0.y);
  r[2] = (short)f2bf(v0.z); r[3] = (short)f2bf(v0.w);
  r[4] = (short)f2bf(v1.x); r[5] = (short)f2bf(v1.y);
  r[6] = (short)f2bf(v1.z); r[7] = (short)f2bf(v1.w);
  return r;
}

// ------- initall: W1 frags [0,128) | Wc [128] | per-chunk bucket histograms [129, 129+NCB) -------
__global__ __launch_bounds__(256) void k_initall(
    const int* __restrict__ ei, int E, int P, int* __restrict__ bcnt, int chunk,
    const float* __restrict__ W1, ushort* __restrict__ Wfr,
    const float* __restrict__ W2, const float* __restrict__ Wfv,
    const float* __restrict__ b2, const float* __restrict__ bfv,
    float* __restrict__ Wc) {
  int b = blockIdx.x;
  if (b < 128) {
    int g = b * 256 + threadIdx.x;
    int ii   = g & 7;
    int lane = (g >> 3) & 63;
    int t    = (g >> 9) & 7;
    int ks   = g >> 12;
    int k = ks * 32 + ((lane >> 4) << 3) + ii;
    int c = t * 16 + (lane & 15);
    Wfr[g] = f2bf(W1[(size_t)k * NH + c]);
  } else if (b == 128) {
    __shared__ float wl[NH];
    if (threadIdx.x < NH) wl[threadIdx.x] = Wfv[threadIdx.x];
    __syncthreads();
    if (threadIdx.x < NH) {
      int i = threadIdx.x;
      const float4* w4 = reinterpret_cast<const float4*>(&W2[(size_t)i * NH]);
      float s = 0.f;
#pragma unroll 8
      for (int k = 0; k < NH / 4; ++k) {
        float4 v = w4[k];
        s += v.x * wl[4 * k] + v.y * wl[4 * k + 1] + v.z * wl[4 * k + 2] + v.w * wl[4 * k + 3];
      }
      Wc[i] = s;
      if (i == 0) {
        float c = 0.f;
        for (int k = 0; k < NH; ++k) c += b2[k] * wl[k];
        Wc[NH] = c + bfv[0];
      }
    }
  } else {
    int cb = b - 129;
    __shared__ int hc[MAXP];
    for (int j = threadIdx.x; j < P; j += 256) hc[j] = 0;
    __syncthreads();
    int start = cb * chunk;
    int endE = min(start + chunk, E);
    for (int e = start + (int)threadIdx.x; e < endE; e += 256)
      atomicAdd(&hc[ei[E + e] >> PSZ_SH], 1);
    __syncthreads();
    for (int j = threadIdx.x; j < P; j += 256) bcnt[cb * P + j] = hc[j];
  }
}

// ---------------- scanA: per-bucket exclusive prefix over chunks; ptot ----------------
__global__ __launch_bounds__(NCB) void k_scanA(const int* __restrict__ bcnt,
                                               int* __restrict__ bloc,
                                               int* __restrict__ ptot, int P) {
  __shared__ int ws[NCB / 64];
  int p = blockIdx.x, tid = threadIdx.x, lane = tid & 63, wid = tid >> 6;
  int v = bcnt[tid * P + p];
  int pre = v;
#pragma unroll
  for (int m = 1; m < 64; m <<= 1) {
    int t = __shfl_up(pre, m, 64);
    if (lane >= m) pre += t;
  }
  if (lane == 63) ws[wid] = pre;
  __syncthreads();
  if (tid == 0) {
    int run = 0;
#pragma unroll
    for (int j = 0; j < NCB / 64; ++j) { int t = ws[j]; ws[j] = run; run += t; }
    ptot[p] = run;
  }
  __syncthreads();
  bloc[tid * P + p] = ws[wid] + pre - v;
}

// ---------------- scanB: exclusive scan of ptot -> pbase ----------------
__global__ __launch_bounds__(1024) void k_scanB(const int* __restrict__ ptot,
                                                int* __restrict__ pbase, int P, int E) {
  __shared__ int ws[16];
  int tid = threadIdx.x, lane = tid & 63, wid = tid >> 6;
  int v = (tid < P) ? ptot[tid] : 0;
  int pre = v;
#pragma unroll
  for (int m = 1; m < 64; m <<= 1) {
    int t = __shfl_up(pre, m, 64);
    if (lane >= m) pre += t;
  }
  if (lane == 63) ws[wid] = pre;
  __syncthreads();
  if (tid == 0) {
    int run = 0;
#pragma unroll
    for (int j = 0; j < 16; ++j) { int t = ws[j]; ws[j] = run; run += t; }
  }
  __syncthreads();
  if (tid < P) pbase[tid] = ws[wid] + pre - v;
  if (tid == 0) pbase[P] = E;
}

// ---------------- scatter: edges -> bucket-contiguous packed sub (LDS cursors) ----------------
__global__ __launch_bounds__(256) void k_scatter(const int* __restrict__ ei, int E,
                                                 const int* __restrict__ pbase,
                                                 const int* __restrict__ bloc,
                                                 uint* __restrict__ sub, int chunk, int P) {
  __shared__ int cur[MAXP];
  int b = blockIdx.x;
  for (int j = threadIdx.x; j < P; j += 256) cur[j] = pbase[j] + bloc[b * P + j];
  __syncthreads();
  int start = b * chunk;
  int endE = min(start + chunk, E);
  for (int e = start + (int)threadIdx.x; e < endE; e += 256) {
    int s = ei[e];
    int d = ei[E + e];
    int pos = atomicAdd(&cur[d >> PSZ_SH], 1);
    sub[pos] = (uint)s | ((uint)(d & ((1 << PSZ_SH) - 1)) << 20);
  }
}

// ---------------- bucket: per-bucket hist -> rowptr/deg/dinv + csr fill (LDS only) ----------------
__global__ __launch_bounds__(256) void k_bucket(const uint* __restrict__ sub,
                                                const int* __restrict__ pbase,
                                                int* __restrict__ rowptr, int* __restrict__ deg,
                                                float* __restrict__ dinv, int* __restrict__ csr,
                                                int N) {
  __shared__ int hist[1 << PSZ_SH];
  __shared__ int curL[1 << PSZ_SH];
  __shared__ int wsum[2];
  const int p = blockIdx.x, tid = threadIdx.x;
  const int base = pbase[p];
  const int cnt = pbase[p + 1] - base;
  const int node0 = p << PSZ_SH;
  if (tid < (1 << PSZ_SH)) hist[tid] = 0;
  __syncthreads();
  for (int e = tid; e < cnt; e += 256) atomicAdd(&hist[sub[base + e] >> 20], 1);
  __syncthreads();
  int d = 0, pre = 0;
  if (tid < (1 << PSZ_SH)) {
    d = hist[tid];
    pre = d;
#pragma unroll
    for (int m = 1; m < 64; m <<= 1) {
      int t = __shfl_up(pre, m, 64);
      if ((tid & 63) >= m) pre += t;
    }
    if ((tid & 63) == 63) wsum[tid >> 6] = pre;
  }
  __syncthreads();
  if (tid < (1 << PSZ_SH)) {
    int excl = base + ((tid >= 64) ? wsum[0] : 0) + pre - d;
    curL[tid] = excl;
    int node = node0 + tid;
    if (node < N) {
      rowptr[node] = excl;
      deg[node] = d;
      dinv[node] = rsqrtf((float)d + 1.0f);
    }
  }
  __syncthreads();
  for (int e = tid; e < cnt; e += 256) {
    uint v = sub[base + e];
    int pos = atomicAdd(&curL[v >> 20], 1);
    csr[pos] = (int)(v & 0xFFFFFu);
  }
}

// ---------------- GEMM1 v3 (MFMA, phase-split MLP): hs = dinv * (x @ W1), bf16 ----------------
__global__ __launch_bounds__(256, 2) void k_gemm1(
    const float* __restrict__ x, const ushort* __restrict__ Wf,
    const float* __restrict__ dinv, ushort* __restrict__ hs, int N) {
  __shared__ ushort Ol[64][136];
  const int tid = threadIdx.x;
  const int w = tid >> 6, l = tid & 63;
  const int row0 = blockIdx.x * 64;
  const int arow = row0 + 16 * w + (l & 15);
  const int kg = l >> 4;
  const bool rv = arow < N;
  const float* xr = &x[(size_t)(rv ? arow : 0) * NF + kg * 8];

  float4 xf0[8], xf1[8];
#pragma unroll
  for (int ks = 0; ks < 8; ++ks) {
    xf0[ks] = *reinterpret_cast<const float4*>(&xr[ks * 32]);
    xf1[ks] = *reinterpret_cast<const float4*>(&xr[ks * 32 + 4]);
  }
  __builtin_amdgcn_sched_barrier(0);

  short8 afr[8];
#pragma unroll
  for (int ks = 0; ks < 8; ++ks) {
    float4 v0 = xf0[ks], v1 = xf1[ks];
    if (!rv) { v0 = make_float4(0.f, 0.f, 0.f, 0.f); v1 = v0; }
    afr[ks] = pack_bf8(v0, v1);
  }

  const short8* Wb = reinterpret_cast<const short8*>(Wf);
  float4v acc[8];
#pragma unroll
  for (int t = 0; t < 8; ++t) acc[t] = (float4v){0.f, 0.f, 0.f, 0.f};
  short8 bc[8], bn[8];
#pragma unroll
  for (int ks = 0; ks < 8; ++ks) bc[ks] = Wb[(ks * 8 + 0) * 64 + l];
#pragma unroll
  for (int tp = 0; tp < 4; ++tp) {
    const int t0 = 2 * tp, t1 = 2 * tp + 1;
#pragma unroll
    for (int ks = 0; ks < 8; ++ks) bn[ks] = Wb[(ks * 8 + t1) * 64 + l];
    __builtin_amdgcn_sched_barrier(0);
#pragma unroll
    for (int ks = 0; ks < 8; ++ks)
      acc[t0] = __builtin_amdgcn_mfma_f32_16x16x32_bf16(afr[ks], bc[ks], acc[t0], 0, 0, 0);
    if (tp < 3) {
#pragma unroll
      for (int ks = 0; ks < 8; ++ks) bc[ks] = Wb[(ks * 8 + t1 + 1) * 64 + l];
      __builtin_amdgcn_sched_barrier(0);
    }
#pragma unroll
    for (int ks = 0; ks < 8; ++ks)
      acc[t1] = __builtin_amdgcn_mfma_f32_16x16x32_bf16(afr[ks], bn[ks], acc[t1], 0, 0, 0);
  }

  float dj[4];
#pragma unroll
  for (int j = 0; j < 4; ++j) {
    int grow = row0 + 16 * w + (l >> 4) * 4 + j;
    dj[j] = (grow < N) ? dinv[grow] : 0.f;
  }
#pragma unroll
  for (int t = 0; t < 8; ++t)
#pragma unroll
    for (int j = 0; j < 4; ++j)
      Ol[16 * w + (l >> 4) * 4 + j][16 * t + (l & 15)] = f2bf(acc[t][j] * dj[j]);
  __syncthreads();
  {
    const int r = tid >> 2, grow = row0 + r;
    if (grow < N) {
      uint* dsts = (uint*)hs;
#pragma unroll
      for (int q = 0; q < 4; ++q) {
        uint4 v = *reinterpret_cast<const uint4*>(&Ol[r][(tid & 3) * 32 + q * 8]);
        *reinterpret_cast<uint4*>(&dsts[(size_t)grow * 64 + (tid & 3) * 16 + q * 4]) = v;
      }
    }
  }
}

// ---------------- fused layer1 gather + relu + dot(Wc): wave/node, quarter-wave edges ----------------
static __device__ __forceinline__ void acc8(float* a, uint4 u) {
  a[0] += bflo(u.x); a[1] += bfhi(u.x);
  a[2] += bflo(u.y); a[3] += bfhi(u.y);
  a[4] += bflo(u.z); a[5] += bfhi(u.z);
  a[6] += bflo(u.w); a[7] += bfhi(u.w);
}

__global__ __launch_bounds__(256) void k_agg1_z(
    const uint4* __restrict__ hs4, const int* __restrict__ rowptr,
    const int* __restrict__ deg, const int* __restrict__ csr,
    const float* __restrict__ dinv, const float* __restrict__ b1,
    const float* __restrict__ Wc, float* __restrict__ zs,
    float* __restrict__ out, int N) {
  int g = blockIdx.x * blockDim.x + threadIdx.x;
  int i = g >> 6;
  if (i >= N) return;
  int lane = threadIdx.x & 63;
  int q = lane >> 4;        // quarter 0..3 -> edge slot
  int sub = lane & 15;      // 16 lanes x uint4 = 128 features

  float a[8];
  {  // self-loop: quarter 0 only
    uint4 u = hs4[(size_t)i * 16 + sub];
    if (q) { u.x = 0u; u.y = 0u; u.z = 0u; u.w = 0u; }
    a[0] = bflo(u.x); a[1] = bfhi(u.x); a[2] = bflo(u.y); a[3] = bfhi(u.y);
    a[4] = bflo(u.z); a[5] = bfhi(u.z); a[6] = bflo(u.w); a[7] = bfhi(u.w);
  }

  int kk = rowptr[i];
  const int end = kk + deg[i];
  for (; kk + 7 < end; kk += 8) {     // 8 edges/iter, 2 per quarter
    int c0 = csr[kk + q];
    int c1 = csr[kk + 4 + q];
    uint4 u0 = hs4[(size_t)c0 * 16 + sub];
    uint4 u1 = hs4[(size_t)c1 * 16 + sub];
    acc8(a, u0);
    acc8(a, u1);
  }
  if (kk + 3 < end) {                 // 4 edges
    int c = csr[kk + q];
    uint4 u = hs4[(size_t)c * 16 + sub];
    acc8(a, u);
    kk += 4;
  }
  int r = end - kk;                   // 0..3 leftover
  if (r > 0) {
    int c = csr[kk + (q < r ? q : r - 1)];
    uint4 u = hs4[(size_t)c * 16 + sub];
    if (q >= r) { u.x = 0u; u.y = 0u; u.z = 0u; u.w = 0u; }
    acc8(a, u);
  }

#pragma unroll
  for (int j = 0; j < 8; ++j) {       // combine quarters
    a[j] += __shfl_xor(a[j], 16, 64);
    a[j] += __shfl_xor(a[j], 32, 64);
  }

  float d = dinv[i];
  float4 ba = reinterpret_cast<const float4*>(b1)[2 * sub];
  float4 bb = reinterpret_cast<const float4*>(b1)[2 * sub + 1];
  float4 wa = reinterpret_cast<const float4*>(Wc)[2 * sub];
  float4 wb = reinterpret_cast<const float4*>(Wc)[2 * sub + 1];
  float s = fmaxf(fmaf(d, a[0], ba.x), 0.f) * wa.x
          + fmaxf(fmaf(d, a[1], ba.y), 0.f) * wa.y
          + fmaxf(fmaf(d, a[2], ba.z), 0.f) * wa.z
          + fmaxf(fmaf(d, a[3], ba.w), 0.f) * wa.w
          + fmaxf(fmaf(d, a[4], bb.x), 0.f) * wb.x
          + fmaxf(fmaf(d, a[5], bb.y), 0.f) * wb.y
          + fmaxf(fmaf(d, a[6], bb.z), 0.f) * wb.z
          + fmaxf(fmaf(d, a[7], bb.w), 0.f) * wb.w;
#pragma unroll
  for (int m = 8; m >= 1; m >>= 1) s += __shfl_xor(s, m, 64);
  if (lane == 0) {
    float zsv = d * s;
    zs[i] = zsv;
    out[i] = d * zsv + Wc[NH];
  }
}

// ---------------- layer2 gather: out[i] += dinv[i] * sum zs[src] ----------------
__global__ void k_out2(const int* __restrict__ rowptr, const int* __restrict__ deg,
                       const int* __restrict__ csr, const float* __restrict__ zs,
                       const float* __restrict__ dinv, float* __restrict__ out, int N) {
  int i = blockIdx.x * blockDim.x + threadIdx.x;
  if (i >= N) return;
  int k = rowptr[i], end = k + deg[i];
  float s = 0.f;
  for (; k + 3 < end; k += 4) {
    float t0 = zs[csr[k]], t1 = zs[csr[k + 1]], t2 = zs[csr[k + 2]], t3 = zs[csr[k + 3]];
    s += (t0 + t1) + (t2 + t3);
  }
  for (; k < end; ++k) s += zs[csr[k]];
  out[i] += dinv[i] * s;
}

extern "C" void kernel_launch(void* const* d_in, const int* in_sizes, int n_in,
                              void* d_out, int out_size, void* d_ws, size_t ws_size,
                              hipStream_t stream) {
  const float* x  = (const float*)d_in[0];
  const int*   ei = (const int*)d_in[1];
  const float* W1 = (const float*)d_in[2];
  const float* b1 = (const float*)d_in[3];
  const float* W2 = (const float*)d_in[4];
  const float* b2 = (const float*)d_in[5];
  const float* Wf = (const float*)d_in[6];
  const float* bf = (const float*)d_in[7];
  const int N = in_sizes[0] / NF;
  const int E = in_sizes[1] / 2;
  const int P = (N + (1 << PSZ_SH) - 1) >> PSZ_SH;   // 782 buckets
  const int chunk = (E + NCB - 1) / NCB;

  char* ws = (char*)d_ws;
  size_t off = 0;
  auto alloc = [&](size_t bytes) {
    void* p = ws + off;
    off = (off + bytes + 255) & ~(size_t)255;
    return p;
  };
  ushort* hs     = (ushort*)alloc((size_t)N * NH * 2);    // 25.6 MB
  ushort* Wfrag  = (ushort*)alloc((size_t)NF * NH * 2);   // 64 KB
  int*    csr    = (int*)alloc((size_t)E * 4);            // 6.4 MB
  uint*   sub    = (uint*)alloc((size_t)E * 4);           // 6.4 MB
  int*    deg    = (int*)alloc((size_t)N * 4);
  int*    rowptr = (int*)alloc((size_t)N * 4);
  float*  dinv   = (float*)alloc((size_t)N * 4);
  float*  zs     = (float*)alloc((size_t)N * 4);
  float*  Wc     = (float*)alloc(132 * 4);
  int*    bcnt   = (int*)alloc((size_t)NCB * P * 4);      // 1.6 MB
  int*    bloc   = (int*)alloc((size_t)NCB * P * 4);      // 1.6 MB
  int*    ptot   = (int*)alloc((size_t)P * 4);
  int*    pbase  = (int*)alloc((size_t)(P + 1) * 4);
  float*  out    = (float*)d_out;

  const int b = 256;
  k_initall<<<129 + NCB, b, 0, stream>>>(ei, E, P, bcnt, chunk,
                                         W1, Wfrag, W2, Wf, b2, bf, Wc);
  k_scanA  <<<P, NCB, 0, stream>>>(bcnt, bloc, ptot, P);
  k_scanB  <<<1, 1024, 0, stream>>>(ptot, pbase, P, E);
  k_scatter<<<NCB, b, 0, stream>>>(ei, E, pbase, bloc, sub, chunk, P);
  k_bucket <<<P, b, 0, stream>>>(sub, pbase, rowptr, deg, dinv, csr, N);
  k_gemm1  <<<(N + 63) / 64, 256, 0, stream>>>(x, Wfrag, dinv, hs, N);
  k_agg1_z <<<(int)(((size_t)N * 64 + b - 1) / b), b, 0, stream>>>(
      (const uint4*)hs, rowptr, deg, csr, dinv, b1, Wc, zs, out, N);
  k_out2   <<<(N + b - 1) / b, b, 0, stream>>>(rowptr, deg, csr, zs, dinv, out, N);
}